// Round 9
// baseline (238.072 us; speedup 1.0000x reference)
//
#include <hip/hip_runtime.h>

// SymmetricContraction: out[n,c,i] = cubic polynomial in x[n,c,:] with
// species/channel-dependent coefficients (968 monomials, padded to 1024).
//   coef[s,t,c,0:4] = mult_t * sum_k u[t,k,i] w[s,k,c]   (fp32)
//   out[n,c,i]      = sum_t coef[idx_n,t,c,i] * x_a x_b x_j
// Pipeline (3 dispatches):
//   coef_setup : coef table (~21 MB ws), u staged in LDS; + block map with
//                XCD-aware species swizzle (species s -> flat block id % 8)
//   contract   : R5 structure: 256 thr, TILE=8 dbuf global_load_lds; 1-D
//                grid through map so same-species blocks share an XCD L2
//   reduce     : out = sum over 8 chunk partials
// ws requirement: ~29.4 MiB.

#define DD     16
#define NATOM  512
#define NCH    128
#define NSPEC  10
#define NT3    816
#define NT2    136
#define NT     968
#define NTP    1024  // 8 chunks x 128 terms
#define ATB    16    // atoms per eval block (same species)
#define APT    4     // atoms per thread
#define MAXB   42    // >= sum_s ceil(cnt_s/ATB)
#define CHUNKS 8
#define NTC    128   // terms per chunk
#define TILE   8     // terms per LDS tile (8 KB fp32)
#define NTILES (NTC / TILE)  // 16
#define CHALF  2     // channel halves (64 ch per block)
#define CT     16    // terms per coef block
#define CLS    544   // worst-case block slots per XCD residue class
#define NBLK   (8 * CLS)  // 4352 grid slots (~85% exit immediately)

#define WS_ORDER 1024
#define WS_MAP   4096
#define WS_COEF  24576
#define COEF_BYTES (NSPEC * NTP * NCH * 16)       // 20,971,520
#define WS_PART  (WS_COEF + COEF_BYTES)           // partials: 8 x 1 MB

// ---------------- compile-time term table ----------------
// pack: a | b<<5 | j<<10 | kind<<15 | mult<<18
// slots in contract: 0..15 -> x[d], 16 -> 1.0f, 17 -> 0.0f
struct TermTable { unsigned v[NTP]; };
constexpr TermTable build_terms() {
  TermTable T{};
  int t = 0;
  for (int a = 0; a < DD; a++)
    for (int b = a; b < DD; b++)
      for (int j = b; j < DD; j++) {
        unsigned m = (a == b && b == j) ? 1u : ((a == b || b == j) ? 3u : 6u);
        T.v[t++] = (unsigned)(a | (b << 5) | (j << 10) | (3u << 15) | (m << 18));
      }
  for (int a = 0; a < DD; a++)
    for (int b = a; b < DD; b++) {
      unsigned m = (a == b) ? 1u : 2u;
      T.v[t++] = (unsigned)(a | (b << 5) | (16 << 10) | (2u << 15) | (m << 18));
    }
  for (int a = 0; a < DD; a++)
    T.v[t++] = (unsigned)(a | (16 << 5) | (16 << 10) | (1u << 15) | (1u << 18));
  while (t < NTP) T.v[t++] = (unsigned)(17 | (17 << 5) | (17 << 10));  // kind=0
  return T;
}
constexpr TermTable TERMS = build_terms();

// ---------------- setup: species bucketing + XCD-swizzled block map -------
__device__ void do_setup(const int* __restrict__ index, int* __restrict__ order,
                         int* __restrict__ map) {
  __shared__ int cnt[NSPEC], cursor[NSPEC], bbase[NSPEC], nb[NSPEC];
  const int tid = threadIdx.x;  // 0..255
  if (tid < NSPEC) { cnt[tid] = 0; cursor[tid] = 0; }
  __syncthreads();
  for (int i = tid; i < NATOM; i += 256) atomicAdd(&cnt[index[i]], 1);
  for (int i = tid; i < MAXB * ATB; i += 256) order[i] = -1;
  for (int i = tid; i < NBLK; i += 256) map[i] = -1;
  __syncthreads();
  if (tid == 0) {
    int base = 0;
    for (int s = 0; s < NSPEC; s++) {
      nb[s] = (cnt[s] + ATB - 1) / ATB;
      bbase[s] = base;
      base += nb[s];
    }
  }
  __syncthreads();
  for (int i = tid; i < NATOM; i += 256) {
    int s = index[i];
    int pos = atomicAdd(&cursor[s], 1);
    order[bbase[s] * ATB + pos] = i;
  }
  if (tid == 0) {
    // species s -> flat block ids == s (mod 8): same-species blocks share an XCD
    int cc[8] = {0, 0, 0, 0, 0, 0, 0, 0};
    for (int s = 0; s < NSPEC; s++) {
      const int r = s & 7;
      for (int ab = 0; ab < nb[s]; ab++)
        for (int ch = 0; ch < CHUNKS; ch++)
          for (int hf = 0; hf < CHALF; hf++) {
            const int slot = r + 8 * cc[r]++;
            map[slot] = (bbase[s] + ab) | (ch << 6) | (hf << 9) | (s << 10);
          }
    }
  }
}

// ---------------- coefficient build (+fused setup), 256 thr ----------------
__global__ __launch_bounds__(256) void coef_setup_kernel(
    const float* __restrict__ u3_0, const float* __restrict__ w3_0,
    const float* __restrict__ u2_0, const float* __restrict__ w2_0,
    const float* __restrict__ u1_0, const float* __restrict__ w1_0,
    const float* __restrict__ u3_1, const float* __restrict__ w3_1,
    const float* __restrict__ u2_1, const float* __restrict__ w2_1,
    const float* __restrict__ u1_1, const float* __restrict__ w1_1,
    const int* __restrict__ index, int* __restrict__ order,
    int* __restrict__ map, float* __restrict__ coef) {
  if (blockIdx.y == NTP / CT) {                // spare row: setup
    if (blockIdx.x == 0) do_setup(index, order, map);
    return;
  }
  const int s = blockIdx.x;
  const int c = threadIdx.x & 127;
  const int h = threadIdx.x >> 7;              // half: terms [h*8, h*8+8)
  const int tbase = blockIdx.y * CT;

  __shared__ float us0[CT][23];
  __shared__ float us1[CT][99];

  // cooperative u staging: each half stages its 8 terms (lane-split per term)
  for (int ii = 0; ii < CT / 2; ++ii) {
    const int i = h * (CT / 2) + ii;
    const unsigned ev = TERMS.v[tbase + i];
    const int kind = (ev >> 15) & 7;
    const int a = ev & 31, b = (ev >> 5) & 31, j = (ev >> 10) & 31;
    if (kind == 3) {
      const int off = (a * DD + b) * DD + j;
      if (c < 23) us0[i][c] = u3_0[off * 23 + c];
      else if (c < 122) us1[i][c - 23] = u3_1[(size_t)off * 99 + (c - 23)];
    } else if (kind == 2) {
      const int off = a * DD + b;
      if (c < 4) us0[i][c] = u2_0[off * 4 + c];
      else if (c < 22) us1[i][c - 4] = u2_1[off * 18 + (c - 4)];
    } else if (kind == 1) {
      if (c < 1) us0[i][0] = u1_0[a];
      else if (c < 4) us1[i][c - 1] = u1_1[a * 3 + (c - 1)];
    }
  }
  __syncthreads();

  float r3_0[23], r3_1[33], r2_0[4], r2_1[6];
#pragma unroll
  for (int k = 0; k < 23; k++) r3_0[k] = w3_0[(s * 23 + k) * NCH + c];
#pragma unroll
  for (int k = 0; k < 33; k++) r3_1[k] = w3_1[(s * 33 + k) * NCH + c];
#pragma unroll
  for (int k = 0; k < 4; k++) r2_0[k] = w2_0[(s * 4 + k) * NCH + c];
#pragma unroll
  for (int k = 0; k < 6; k++) r2_1[k] = w2_1[(s * 6 + k) * NCH + c];
  const float r1_0 = w1_0[s * NCH + c];
  const float r1_1 = w1_1[s * NCH + c];

  for (int ii = 0; ii < CT / 2; ++ii) {
    const int i = h * (CT / 2) + ii;
    const unsigned ev = TERMS.v[tbase + i];
    const int kind = (ev >> 15) & 7;
    const float fm = (float)((ev >> 18) & 7);
    float s0 = 0.f, s1 = 0.f, s2 = 0.f, s3 = 0.f;
    if (kind == 3) {
#pragma unroll
      for (int k = 0; k < 23; k++) s0 += us0[i][k] * r3_0[k];
#pragma unroll
      for (int k = 0; k < 33; k++) {
        const float w = r3_1[k];
        s1 += us1[i][k * 3 + 0] * w;
        s2 += us1[i][k * 3 + 1] * w;
        s3 += us1[i][k * 3 + 2] * w;
      }
    } else if (kind == 2) {
#pragma unroll
      for (int k = 0; k < 4; k++) s0 += us0[i][k] * r2_0[k];
#pragma unroll
      for (int k = 0; k < 6; k++) {
        const float w = r2_1[k];
        s1 += us1[i][k * 3 + 0] * w;
        s2 += us1[i][k * 3 + 1] * w;
        s3 += us1[i][k * 3 + 2] * w;
      }
    } else if (kind == 1) {
      s0 = us0[i][0] * r1_0;
      s1 = us1[i][0] * r1_1;
      s2 = us1[i][1] * r1_1;
      s3 = us1[i][2] * r1_1;
    }
    *(float4*)(coef + ((size_t)(s * NTP + tbase + i) * NCH + c) * 4) =
        float4{fm * s0, fm * s1, fm * s2, fm * s3};
  }
}

// ---------------- contract: LDS-pipelined polynomial eval ----------------
__device__ __forceinline__ void stage_tile(const float* __restrict__ lane_base,
                                           int t0_tile, float* dst_base, int wave) {
#pragma unroll
  for (int r = 0; r < 2; ++r) {
    const int term = wave * 2 + r;                  // 4 waves x 2 = 8 terms
    const float* g = lane_base + (size_t)(t0_tile + term) * (NCH * 4);
    float* l = dst_base + term * 256;               // 64 lanes x 4 floats
    __builtin_amdgcn_global_load_lds(
        (const __attribute__((address_space(1))) unsigned int*)g,
        (__attribute__((address_space(3))) unsigned int*)l, 16, 0, 0);
  }
}

template <int CH>
__device__ __forceinline__ void eval_chunk(const float* __restrict__ lane_base,
                                           float (*lbuf)[TILE * 256],
                                           int wave, int lane,
                                           const float (&xr)[APT][18],
                                           float (&ac)[APT][4]) {
  constexpr int T0 = CH * NTC;
  stage_tile(lane_base, T0, &lbuf[0][0], wave);
#pragma unroll
  for (int tile = 0; tile < NTILES; ++tile) {
    __syncthreads();  // drains vmcnt -> lbuf[tile&1] ready; prev compute done
    if (tile + 1 < NTILES)
      stage_tile(lane_base, T0 + (tile + 1) * TILE, &lbuf[(tile + 1) & 1][0], wave);
    const float* lb = &lbuf[tile & 1][0];
#pragma unroll
    for (int i = 0; i < TILE; ++i) {
      const unsigned ev = TERMS.v[T0 + tile * TILE + i];  // compile-time const
      const int ea = ev & 31, eb = (ev >> 5) & 31, ej = (ev >> 10) & 31;
      const float4 cf = *(const float4*)(lb + (i * 64 + lane) * 4);
#pragma unroll
      for (int k = 0; k < APT; ++k) {
        const float m = xr[k][ea] * xr[k][eb] * xr[k][ej];
        ac[k][0] += cf.x * m; ac[k][1] += cf.y * m;
        ac[k][2] += cf.z * m; ac[k][3] += cf.w * m;
      }
    }
  }
}

__device__ __forceinline__ void load16(float (&xr)[18], const float* __restrict__ p) {
  const float4* q = (const float4*)p;
  const float4 v0 = q[0], v1 = q[1], v2 = q[2], v3 = q[3];
  xr[0] = v0.x; xr[1] = v0.y; xr[2] = v0.z; xr[3] = v0.w;
  xr[4] = v1.x; xr[5] = v1.y; xr[6] = v1.z; xr[7] = v1.w;
  xr[8] = v2.x; xr[9] = v2.y; xr[10] = v2.z; xr[11] = v2.w;
  xr[12] = v3.x; xr[13] = v3.y; xr[14] = v3.z; xr[15] = v3.w;
}

__global__ __launch_bounds__(256, 4) void contract_kernel(const float* __restrict__ x,
                                                          const int* __restrict__ order,
                                                          const int* __restrict__ map,
                                                          const float* __restrict__ coef,
                                                          float* __restrict__ partial) {
  const int mv = map[blockIdx.x];
  if (mv < 0) return;                          // idle slot (uniform per block)
  const int ab    = mv & 63;
  const int chunk = (mv >> 6) & 7;
  const int hf    = (mv >> 9) & 1;
  const int s     = (mv >> 10) & 15;

  const int lane = threadIdx.x & 63;
  const int wave = threadIdx.x >> 6;           // == atom group 0..3
  const int c = hf * 64 + lane;

  __shared__ float lbuf[2][TILE * 256];        // 2 x 8 KB

  int n[APT];
#pragma unroll
  for (int k = 0; k < APT; k++) n[k] = order[ab * ATB + wave * APT + k];

  float xr[APT][18];
#pragma unroll
  for (int k = 0; k < APT; k++) {
#pragma unroll
    for (int i = 0; i < DD; i++) xr[k][i] = 0.f;
    xr[k][16] = 1.f;
    xr[k][17] = 0.f;
  }
#pragma unroll
  for (int k = 0; k < APT; k++)
    if (n[k] >= 0) load16(xr[k], x + ((size_t)n[k] * NCH + c) * DD);

  float ac[APT][4];
#pragma unroll
  for (int k = 0; k < APT; k++) { ac[k][0] = 0.f; ac[k][1] = 0.f; ac[k][2] = 0.f; ac[k][3] = 0.f; }

  const float* lane_base = coef + ((size_t)s * NTP * NCH + (size_t)hf * 64 + lane) * 4;

  switch (chunk) {
    case 0:  eval_chunk<0>(lane_base, lbuf, wave, lane, xr, ac); break;
    case 1:  eval_chunk<1>(lane_base, lbuf, wave, lane, xr, ac); break;
    case 2:  eval_chunk<2>(lane_base, lbuf, wave, lane, xr, ac); break;
    case 3:  eval_chunk<3>(lane_base, lbuf, wave, lane, xr, ac); break;
    case 4:  eval_chunk<4>(lane_base, lbuf, wave, lane, xr, ac); break;
    case 5:  eval_chunk<5>(lane_base, lbuf, wave, lane, xr, ac); break;
    case 6:  eval_chunk<6>(lane_base, lbuf, wave, lane, xr, ac); break;
    default: eval_chunk<7>(lane_base, lbuf, wave, lane, xr, ac); break;
  }

  float* pb = partial + (size_t)chunk * (NATOM * NCH * 4);
#pragma unroll
  for (int k = 0; k < APT; k++)
    if (n[k] >= 0)
      *(float4*)(pb + ((size_t)n[k] * NCH + c) * 4) =
          float4{ac[k][0], ac[k][1], ac[k][2], ac[k][3]};
}

// ---------------- final reduction over chunks ----------------
__global__ __launch_bounds__(256) void reduce_kernel(const float4* __restrict__ partial,
                                                     float4* __restrict__ out) {
  const int i = blockIdx.x * 256 + threadIdx.x;  // 0 .. NATOM*NCH-1
  float4 s{0.f, 0.f, 0.f, 0.f};
#pragma unroll
  for (int ch = 0; ch < CHUNKS; ch++) {
    const float4 v = partial[(size_t)ch * (NATOM * NCH) + i];
    s.x += v.x; s.y += v.y; s.z += v.z; s.w += v.w;
  }
  out[i] = s;
}

extern "C" void kernel_launch(void* const* d_in, const int* in_sizes, int n_in,
                              void* d_out, int out_size, void* d_ws, size_t ws_size,
                              hipStream_t stream) {
  const float* x    = (const float*)d_in[0];
  const int* index  = (const int*)d_in[1];
  const float* u3_0 = (const float*)d_in[2];
  const float* w3_0 = (const float*)d_in[3];
  const float* u2_0 = (const float*)d_in[4];
  const float* w2_0 = (const float*)d_in[5];
  const float* u1_0 = (const float*)d_in[6];
  const float* w1_0 = (const float*)d_in[7];
  const float* u3_1 = (const float*)d_in[8];
  const float* w3_1 = (const float*)d_in[9];
  const float* u2_1 = (const float*)d_in[10];
  const float* w2_1 = (const float*)d_in[11];
  const float* u1_1 = (const float*)d_in[12];
  const float* w1_1 = (const float*)d_in[13];
  float* out = (float*)d_out;

  char* ws = (char*)d_ws;
  int* order     = (int*)(ws + WS_ORDER);
  int* map       = (int*)(ws + WS_MAP);
  float* coef    = (float*)(ws + WS_COEF);
  float* partial = (float*)(ws + WS_PART);

  coef_setup_kernel<<<dim3(NSPEC, NTP / CT + 1), 256, 0, stream>>>(
      u3_0, w3_0, u2_0, w2_0, u1_0, w1_0,
      u3_1, w3_1, u2_1, w2_1, u1_1, w1_1, index, order, map, coef);
  contract_kernel<<<NBLK, 256, 0, stream>>>(x, order, map, coef, partial);
  reduce_kernel<<<(NATOM * NCH) / 256, 256, 0, stream>>>((const float4*)partial, (float4*)out);
}

// Round 10
// 162.890 us; speedup vs baseline: 1.4615x; 1.4615x over previous
//
#include <hip/hip_runtime.h>

// SymmetricContraction: out[n,c,i] = cubic polynomial in x[n,c,:] with
// species/channel-dependent coefficients (968 monomials, padded to 1024).
//   coef[s,t,c,0:4] = mult_t * sum_k u[t,k,i] w[s,k,c]   (fp32)
//   out[n,c,i]      = sum_t coef[idx_n,t,c,i] * x_a x_b x_j
// Pipeline (3 dispatches):
//   coef_setup : coef table (~21 MB ws), u staged in LDS; 256 thr
//   contract   : BARRIER-FREE wave-private pipeline. Each wave owns 16
//                channels; stages its own 2KB tile slice via global_load_lds
//                and throttles with explicit s_waitcnt vmcnt(N) (never 0
//                mid-stream). 3 tiles in flight/wave, 4-deep LDS ring.
//   reduce     : out = sum over 8 chunk partials
// ws requirement: ~29.4 MiB.

#define DD     16
#define NATOM  512
#define NCH    128
#define NSPEC  10
#define NT3    816
#define NT2    136
#define NT     968
#define NTP    1024  // 8 chunks x 128 terms
#define ATB    16    // atoms per eval block (same species)
#define APT    4     // atoms per thread
#define MAXB   42    // >= sum_s ceil(cnt_s/ATB)
#define CHUNKS 8
#define NTC    128   // terms per chunk
#define TILE   8     // terms per tile
#define NTILES (NTC / TILE)  // 16
#define CHALF  2     // channel halves (64 ch per block)
#define CT     16    // terms per coef block
#define NWV    4     // waves per contract block
#define CPW    16    // channels per wave
#define DEPTH  4     // LDS ring depth (3 tiles in flight + current)
#define SLICE  (TILE * CPW * 4)   // 512 floats = 2 KB per tile slice

#define WS_DESC  0
#define WS_ORDER 1024
#define WS_COEF  8192
#define COEF_BYTES (NSPEC * NTP * NCH * 16)       // 20,971,520
#define WS_PART  (WS_COEF + COEF_BYTES)           // partials: 8 x 1 MB

// ---------------- compile-time term table ----------------
// pack: a | b<<5 | j<<10 | kind<<15 | mult<<18
// slots in contract: 0..15 -> x[d], 16 -> 1.0f, 17 -> 0.0f
struct TermTable { unsigned v[NTP]; };
constexpr TermTable build_terms() {
  TermTable T{};
  int t = 0;
  for (int a = 0; a < DD; a++)
    for (int b = a; b < DD; b++)
      for (int j = b; j < DD; j++) {
        unsigned m = (a == b && b == j) ? 1u : ((a == b || b == j) ? 3u : 6u);
        T.v[t++] = (unsigned)(a | (b << 5) | (j << 10) | (3u << 15) | (m << 18));
      }
  for (int a = 0; a < DD; a++)
    for (int b = a; b < DD; b++) {
      unsigned m = (a == b) ? 1u : 2u;
      T.v[t++] = (unsigned)(a | (b << 5) | (16 << 10) | (2u << 15) | (m << 18));
    }
  for (int a = 0; a < DD; a++)
    T.v[t++] = (unsigned)(a | (16 << 5) | (16 << 10) | (1u << 15) | (1u << 18));
  while (t < NTP) T.v[t++] = (unsigned)(17 | (17 << 5) | (17 << 10));  // kind=0
  return T;
}
constexpr TermTable TERMS = build_terms();

// ---------------- setup: species bucketing ----------------
__device__ void do_setup(const int* __restrict__ index, int* __restrict__ desc,
                         int* __restrict__ order) {
  __shared__ int cnt[NSPEC], cursor[NSPEC], bbase[NSPEC + 1];
  const int tid = threadIdx.x;  // 0..255
  if (tid < NSPEC) { cnt[tid] = 0; cursor[tid] = 0; }
  __syncthreads();
  for (int i = tid; i < NATOM; i += 256) atomicAdd(&cnt[index[i]], 1);
  for (int i = tid; i < MAXB * ATB; i += 256) order[i] = -1;
  __syncthreads();
  if (tid == 0) {
    int base = 0;
    for (int s = 0; s < NSPEC; s++) { bbase[s] = base; base += (cnt[s] + ATB - 1) / ATB; }
    bbase[NSPEC] = base;
  }
  __syncthreads();
  for (int i = tid; i < NATOM; i += 256) {
    int s = index[i];
    int pos = atomicAdd(&cursor[s], 1);
    order[bbase[s] * ATB + pos] = i;
  }
  for (int i = tid; i < MAXB; i += 256) {
    int sp = -1;
    for (int s = 0; s < NSPEC; s++)
      if (i >= bbase[s] && i < bbase[s + 1]) sp = s;
    desc[i] = sp;
  }
}

// ---------------- coefficient build (+fused setup), 256 thr ----------------
__global__ __launch_bounds__(256) void coef_setup_kernel(
    const float* __restrict__ u3_0, const float* __restrict__ w3_0,
    const float* __restrict__ u2_0, const float* __restrict__ w2_0,
    const float* __restrict__ u1_0, const float* __restrict__ w1_0,
    const float* __restrict__ u3_1, const float* __restrict__ w3_1,
    const float* __restrict__ u2_1, const float* __restrict__ w2_1,
    const float* __restrict__ u1_1, const float* __restrict__ w1_1,
    const int* __restrict__ index, int* __restrict__ desc,
    int* __restrict__ order, float* __restrict__ coef) {
  if (blockIdx.y == NTP / CT) {                // spare row: setup
    if (blockIdx.x == 0) do_setup(index, desc, order);
    return;
  }
  const int s = blockIdx.x;
  const int c = threadIdx.x & 127;
  const int h = threadIdx.x >> 7;              // half: terms [h*8, h*8+8)
  const int tbase = blockIdx.y * CT;

  __shared__ float us0[CT][23];
  __shared__ float us1[CT][99];

  // cooperative u staging: each half stages its 8 terms (lane-split per term)
  for (int ii = 0; ii < CT / 2; ++ii) {
    const int i = h * (CT / 2) + ii;
    const unsigned ev = TERMS.v[tbase + i];
    const int kind = (ev >> 15) & 7;
    const int a = ev & 31, b = (ev >> 5) & 31, j = (ev >> 10) & 31;
    if (kind == 3) {
      const int off = (a * DD + b) * DD + j;
      if (c < 23) us0[i][c] = u3_0[off * 23 + c];
      else if (c < 122) us1[i][c - 23] = u3_1[(size_t)off * 99 + (c - 23)];
    } else if (kind == 2) {
      const int off = a * DD + b;
      if (c < 4) us0[i][c] = u2_0[off * 4 + c];
      else if (c < 22) us1[i][c - 4] = u2_1[off * 18 + (c - 4)];
    } else if (kind == 1) {
      if (c < 1) us0[i][0] = u1_0[a];
      else if (c < 4) us1[i][c - 1] = u1_1[a * 3 + (c - 1)];
    }
  }
  __syncthreads();

  float r3_0[23], r3_1[33], r2_0[4], r2_1[6];
#pragma unroll
  for (int k = 0; k < 23; k++) r3_0[k] = w3_0[(s * 23 + k) * NCH + c];
#pragma unroll
  for (int k = 0; k < 33; k++) r3_1[k] = w3_1[(s * 33 + k) * NCH + c];
#pragma unroll
  for (int k = 0; k < 4; k++) r2_0[k] = w2_0[(s * 4 + k) * NCH + c];
#pragma unroll
  for (int k = 0; k < 6; k++) r2_1[k] = w2_1[(s * 6 + k) * NCH + c];
  const float r1_0 = w1_0[s * NCH + c];
  const float r1_1 = w1_1[s * NCH + c];

  for (int ii = 0; ii < CT / 2; ++ii) {
    const int i = h * (CT / 2) + ii;
    const unsigned ev = TERMS.v[tbase + i];
    const int kind = (ev >> 15) & 7;
    const float fm = (float)((ev >> 18) & 7);
    float s0 = 0.f, s1 = 0.f, s2 = 0.f, s3 = 0.f;
    if (kind == 3) {
#pragma unroll
      for (int k = 0; k < 23; k++) s0 += us0[i][k] * r3_0[k];
#pragma unroll
      for (int k = 0; k < 33; k++) {
        const float w = r3_1[k];
        s1 += us1[i][k * 3 + 0] * w;
        s2 += us1[i][k * 3 + 1] * w;
        s3 += us1[i][k * 3 + 2] * w;
      }
    } else if (kind == 2) {
#pragma unroll
      for (int k = 0; k < 4; k++) s0 += us0[i][k] * r2_0[k];
#pragma unroll
      for (int k = 0; k < 6; k++) {
        const float w = r2_1[k];
        s1 += us1[i][k * 3 + 0] * w;
        s2 += us1[i][k * 3 + 1] * w;
        s3 += us1[i][k * 3 + 2] * w;
      }
    } else if (kind == 1) {
      s0 = us0[i][0] * r1_0;
      s1 = us1[i][0] * r1_1;
      s2 = us1[i][1] * r1_1;
      s3 = us1[i][2] * r1_1;
    }
    *(float4*)(coef + ((size_t)(s * NTP + tbase + i) * NCH + c) * 4) =
        float4{fm * s0, fm * s1, fm * s2, fm * s3};
  }
}

// ---------------- contract: barrier-free wave-private pipeline ----------------
template <int N>
__device__ __forceinline__ void waitcnt_vm() {
  asm volatile("s_waitcnt vmcnt(%0)" ::"n"(N) : "memory");
}
__device__ __forceinline__ void waitcnt_lgkm0() {
  asm volatile("s_waitcnt lgkmcnt(0)" ::: "memory");
}

// Stage one tile slice (8 terms x 16 ch x 16 B = 2 KB) for this wave.
// pbase already includes s, c, and lane's term-subgroup (lane>>4).
__device__ __forceinline__ void stage_tile(const float* __restrict__ pbase,
                                           int term0, float* slice) {
#pragma unroll
  for (int r = 0; r < 2; ++r) {
    const float* g = pbase + (size_t)(term0 + 4 * r) * (NCH * 4);
    __builtin_amdgcn_global_load_lds(
        (const __attribute__((address_space(1))) unsigned int*)g,
        (__attribute__((address_space(3))) unsigned int*)(slice + r * 256), 16, 0, 0);
  }
}

template <int TB>
__device__ __forceinline__ void compute_tile(const float* __restrict__ slice, int chl,
                                             const float (&xr)[APT][18],
                                             float (&ac)[APT][4]) {
#pragma unroll
  for (int i = 0; i < TILE; ++i) {
    const unsigned ev = TERMS.v[TB + i];  // compile-time constant
    const int ea = ev & 31, eb = (ev >> 5) & 31, ej = (ev >> 10) & 31;
    const float4 cf = *(const float4*)(slice + i * 64 + chl * 4);
#pragma unroll
    for (int k = 0; k < APT; ++k) {
      const float m = xr[k][ea] * xr[k][eb] * xr[k][ej];
      ac[k][0] += cf.x * m; ac[k][1] += cf.y * m;
      ac[k][2] += cf.z * m; ac[k][3] += cf.w * m;
    }
  }
}

template <int CH, int T>
struct Pipe {
  static __device__ __forceinline__ void run(const float* __restrict__ pbase,
                                             float* __restrict__ ws, int chl,
                                             const float (&xr)[APT][18],
                                             float (&ac)[APT][4]) {
    constexpr int T0 = CH * NTC;
    waitcnt_lgkm0();  // ds_reads of tile T-1 done before its buffer is reused
    if constexpr (T + 3 < NTILES)
      stage_tile(pbase, T0 + (T + 3) * TILE, ws + ((T + 3) & 3) * SLICE);
    constexpr int LEFT = (NTILES - 1 - T) < 3 ? (NTILES - 1 - T) : 3;
    waitcnt_vm<2 * LEFT>();  // tile T landed; up to 3 tiles stay in flight
    compute_tile<T0 + T * TILE>(ws + (T & 3) * SLICE, chl, xr, ac);
    if constexpr (T + 1 < NTILES) Pipe<CH, T + 1>::run(pbase, ws, chl, xr, ac);
  }
};

__device__ __forceinline__ void load16(float (&xr)[18], const float* __restrict__ p) {
  const float4* q = (const float4*)p;
  const float4 v0 = q[0], v1 = q[1], v2 = q[2], v3 = q[3];
  xr[0] = v0.x; xr[1] = v0.y; xr[2] = v0.z; xr[3] = v0.w;
  xr[4] = v1.x; xr[5] = v1.y; xr[6] = v1.z; xr[7] = v1.w;
  xr[8] = v2.x; xr[9] = v2.y; xr[10] = v2.z; xr[11] = v2.w;
  xr[12] = v3.x; xr[13] = v3.y; xr[14] = v3.z; xr[15] = v3.w;
}

__global__ __launch_bounds__(256, 4) void contract_kernel(const float* __restrict__ x,
                                                          const int* __restrict__ desc,
                                                          const int* __restrict__ order,
                                                          const float* __restrict__ coef,
                                                          float* __restrict__ partial) {
  const int s = desc[blockIdx.x];
  if (s < 0) return;                           // uniform per block
  const int lane = threadIdx.x & 63;
  const int wave = threadIdx.x >> 6;           // channel quarter 0..3
  const int ag   = lane >> 4;                  // atom group 0..3 (4 atoms each)
  const int chl  = lane & 15;                  // channel within wave
  const int c    = blockIdx.z * 64 + wave * CPW + chl;

  __shared__ float lbuf[NWV * DEPTH * SLICE];  // 32 KB
  float* ws = lbuf + wave * (DEPTH * SLICE);

  int n[APT];
#pragma unroll
  for (int k = 0; k < APT; k++) n[k] = order[blockIdx.x * ATB + ag * APT + k];

  float xr[APT][18];
#pragma unroll
  for (int k = 0; k < APT; k++) {
#pragma unroll
    for (int i = 0; i < DD; i++) xr[k][i] = 0.f;
    xr[k][16] = 1.f;
    xr[k][17] = 0.f;
  }
#pragma unroll
  for (int k = 0; k < APT; k++)
    if (n[k] >= 0) load16(xr[k], x + ((size_t)n[k] * NCH + c) * DD);

  float ac[APT][4];
#pragma unroll
  for (int k = 0; k < APT; k++) { ac[k][0] = 0.f; ac[k][1] = 0.f; ac[k][2] = 0.f; ac[k][3] = 0.f; }

  // per-lane global base: species slab + lane's term subgroup + channel
  const float* pbase =
      coef + (size_t)s * NTP * NCH * 4 + (size_t)ag * (NCH * 4) + (size_t)c * 4;

  const int chunk = blockIdx.y;
  switch (chunk) {
    case 0: { constexpr int C0 = 0;
      stage_tile(pbase, C0 * NTC + 0, ws + 0 * SLICE);
      stage_tile(pbase, C0 * NTC + 8, ws + 1 * SLICE);
      stage_tile(pbase, C0 * NTC + 16, ws + 2 * SLICE);
      Pipe<C0, 0>::run(pbase, ws, chl, xr, ac); } break;
    case 1: { constexpr int C0 = 1;
      stage_tile(pbase, C0 * NTC + 0, ws + 0 * SLICE);
      stage_tile(pbase, C0 * NTC + 8, ws + 1 * SLICE);
      stage_tile(pbase, C0 * NTC + 16, ws + 2 * SLICE);
      Pipe<C0, 0>::run(pbase, ws, chl, xr, ac); } break;
    case 2: { constexpr int C0 = 2;
      stage_tile(pbase, C0 * NTC + 0, ws + 0 * SLICE);
      stage_tile(pbase, C0 * NTC + 8, ws + 1 * SLICE);
      stage_tile(pbase, C0 * NTC + 16, ws + 2 * SLICE);
      Pipe<C0, 0>::run(pbase, ws, chl, xr, ac); } break;
    case 3: { constexpr int C0 = 3;
      stage_tile(pbase, C0 * NTC + 0, ws + 0 * SLICE);
      stage_tile(pbase, C0 * NTC + 8, ws + 1 * SLICE);
      stage_tile(pbase, C0 * NTC + 16, ws + 2 * SLICE);
      Pipe<C0, 0>::run(pbase, ws, chl, xr, ac); } break;
    case 4: { constexpr int C0 = 4;
      stage_tile(pbase, C0 * NTC + 0, ws + 0 * SLICE);
      stage_tile(pbase, C0 * NTC + 8, ws + 1 * SLICE);
      stage_tile(pbase, C0 * NTC + 16, ws + 2 * SLICE);
      Pipe<C0, 0>::run(pbase, ws, chl, xr, ac); } break;
    case 5: { constexpr int C0 = 5;
      stage_tile(pbase, C0 * NTC + 0, ws + 0 * SLICE);
      stage_tile(pbase, C0 * NTC + 8, ws + 1 * SLICE);
      stage_tile(pbase, C0 * NTC + 16, ws + 2 * SLICE);
      Pipe<C0, 0>::run(pbase, ws, chl, xr, ac); } break;
    case 6: { constexpr int C0 = 6;
      stage_tile(pbase, C0 * NTC + 0, ws + 0 * SLICE);
      stage_tile(pbase, C0 * NTC + 8, ws + 1 * SLICE);
      stage_tile(pbase, C0 * NTC + 16, ws + 2 * SLICE);
      Pipe<C0, 0>::run(pbase, ws, chl, xr, ac); } break;
    default: { constexpr int C0 = 7;
      stage_tile(pbase, C0 * NTC + 0, ws + 0 * SLICE);
      stage_tile(pbase, C0 * NTC + 8, ws + 1 * SLICE);
      stage_tile(pbase, C0 * NTC + 16, ws + 2 * SLICE);
      Pipe<C0, 0>::run(pbase, ws, chl, xr, ac); } break;
  }

  float* pb = partial + (size_t)chunk * (NATOM * NCH * 4);
#pragma unroll
  for (int k = 0; k < APT; k++)
    if (n[k] >= 0)
      *(float4*)(pb + ((size_t)n[k] * NCH + c) * 4) =
          float4{ac[k][0], ac[k][1], ac[k][2], ac[k][3]};
}

// ---------------- final reduction over chunks ----------------
__global__ __launch_bounds__(256) void reduce_kernel(const float4* __restrict__ partial,
                                                     float4* __restrict__ out) {
  const int i = blockIdx.x * 256 + threadIdx.x;  // 0 .. NATOM*NCH-1
  float4 s{0.f, 0.f, 0.f, 0.f};
#pragma unroll
  for (int ch = 0; ch < CHUNKS; ch++) {
    const float4 v = partial[(size_t)ch * (NATOM * NCH) + i];
    s.x += v.x; s.y += v.y; s.z += v.z; s.w += v.w;
  }
  out[i] = s;
}

extern "C" void kernel_launch(void* const* d_in, const int* in_sizes, int n_in,
                              void* d_out, int out_size, void* d_ws, size_t ws_size,
                              hipStream_t stream) {
  const float* x    = (const float*)d_in[0];
  const int* index  = (const int*)d_in[1];
  const float* u3_0 = (const float*)d_in[2];
  const float* w3_0 = (const float*)d_in[3];
  const float* u2_0 = (const float*)d_in[4];
  const float* w2_0 = (const float*)d_in[5];
  const float* u1_0 = (const float*)d_in[6];
  const float* w1_0 = (const float*)d_in[7];
  const float* u3_1 = (const float*)d_in[8];
  const float* w3_1 = (const float*)d_in[9];
  const float* u2_1 = (const float*)d_in[10];
  const float* w2_1 = (const float*)d_in[11];
  const float* u1_1 = (const float*)d_in[12];
  const float* w1_1 = (const float*)d_in[13];
  float* out = (float*)d_out;

  char* ws = (char*)d_ws;
  int* desc      = (int*)(ws + WS_DESC);
  int* order     = (int*)(ws + WS_ORDER);
  float* coef    = (float*)(ws + WS_COEF);
  float* partial = (float*)(ws + WS_PART);

  coef_setup_kernel<<<dim3(NSPEC, NTP / CT + 1), 256, 0, stream>>>(
      u3_0, w3_0, u2_0, w2_0, u1_0, w1_0,
      u3_1, w3_1, u2_1, w2_1, u1_1, w1_1, index, desc, order, coef);
  contract_kernel<<<dim3(MAXB, CHUNKS, CHALF), 256, 0, stream>>>(x, desc, order, coef, partial);
  reduce_kernel<<<(NATOM * NCH) / 256, 256, 0, stream>>>((const float4*)partial, (float4*)out);
}